// Round 4
// baseline (641.016 us; speedup 1.0000x reference)
//
#include <hip/hip_runtime.h>

#define N_V 35709
#define N_F 70789
#define NR  (3*N_V)   // 107127
#define NB  64

// ws layout (floats):
//   rotM  : NB*9   = 576    @ 0
//   gm    : NB*27  = 1728   @ 576
//   ctrS  : 144*NB = 9216   @ 2304   (id+ex coeffs, [j][b])
//   ctrT  : 80*NB  = 5120   @ 11520  (tex coeffs, [j][b])
//   shapeT: NR*64          @ 16640   (pre-rotation face_shape, TRANSPOSED [i][b])
//   texT  : NR*64          @ 16640+NR*64
#define WS_ROT    0
#define WS_GM     576
#define WS_CTRS   2304
#define WS_CTRT   11520
#define WS_SHAPET 16640

__global__ __launch_bounds__(64) void k_setup_rot(
    const float* __restrict__ coeffs, const float* __restrict__ init_lit,
    float* __restrict__ rotM, float* __restrict__ gm)
{
    int b = threadIdx.x;
    const float* cb = coeffs + b * 257;

    float ax = cb[224], ay = cb[225], az = cb[226];
    float cx = cosf(ax), sx = sinf(ax);
    float cy = cosf(ay), sy = sinf(ay);
    float cz = cosf(az), sz = sinf(az);
    float m[9];
    m[0] = cz * cy;
    m[1] = cz * sy * sx - sz * cx;
    m[2] = sz * sx + cz * sy * cx;
    m[3] = sz * cy;
    m[4] = cz * cx + sz * sy * sx;
    m[5] = sz * sy * cx - cz * sx;
    m[6] = -sy;
    m[7] = cy * sx;
    m[8] = cy * cx;
#pragma unroll
    for (int k = 0; k < 9; k++) rotM[b * 9 + k] = m[k];

#pragma unroll
    for (int k = 0; k < 9; k++) {
        float il = init_lit[k];
#pragma unroll
        for (int c = 0; c < 3; c++)
            gm[b * 27 + k * 3 + c] = cb[227 + c * 9 + k] + il;
    }
}

__global__ __launch_bounds__(64) void k_transpose(
    const float* __restrict__ coeffs,
    float* __restrict__ ctrS, float* __restrict__ ctrT)
{
    int j = blockIdx.x;
    int b = threadIdx.x;
    float v = coeffs[b * 257 + j];
    if (j < 144) ctrS[j * 64 + b] = v;
    else         ctrT[(j - 144) * 64 + b] = v;
}

// lane = batch. Wave owns 16 consecutive rows; block (4 waves) owns 64 rows.
// Coefs: coalesced vector loads, register-resident, reused x16 rows.
// Base rows: wave-uniform addresses -> SMEM scalar loads.
// Stores: row-major [i][64] -> naturally coalesced 256-B per row.
__global__ __launch_bounds__(256) void k_gemm(
    const float* __restrict__ idBase, const float* __restrict__ exBase,
    const float* __restrict__ texBase, const float* __restrict__ meanshape,
    const float* __restrict__ meantex,
    const float* __restrict__ ctrS, const float* __restrict__ ctrT,
    float* __restrict__ shapeT, float* __restrict__ texT, int tex_transposed)
{
    int w    = threadIdx.x >> 6;
    int lane = threadIdx.x & 63;
    int r0   = blockIdx.x * 64 + w * 16;

    float acc[16];

    // ---------------- shape: idBase (j 0..79) + exBase (j 0..63) ----------------
#pragma unroll
    for (int r = 0; r < 16; r++) acc[r] = 0.f;

#pragma unroll 2
    for (int jt = 0; jt < 10; jt++) {
        float ct[8];
#pragma unroll
        for (int u = 0; u < 8; u++) ct[u] = ctrS[(jt * 8 + u) * 64 + lane];
#pragma unroll
        for (int r = 0; r < 16; r++) {
            int row = r0 + r; if (row >= NR) row = NR - 1;   // uniform
            const float* bp = idBase + (size_t)row * 80 + jt * 8;
            acc[r] += bp[0] * ct[0];
            acc[r] += bp[1] * ct[1];
            acc[r] += bp[2] * ct[2];
            acc[r] += bp[3] * ct[3];
            acc[r] += bp[4] * ct[4];
            acc[r] += bp[5] * ct[5];
            acc[r] += bp[6] * ct[6];
            acc[r] += bp[7] * ct[7];
        }
    }
#pragma unroll 2
    for (int jt = 0; jt < 8; jt++) {
        float ct[8];
#pragma unroll
        for (int u = 0; u < 8; u++) ct[u] = ctrS[(80 + jt * 8 + u) * 64 + lane];
#pragma unroll
        for (int r = 0; r < 16; r++) {
            int row = r0 + r; if (row >= NR) row = NR - 1;
            const float* bp = exBase + (size_t)row * 64 + jt * 8;
            acc[r] += bp[0] * ct[0];
            acc[r] += bp[1] * ct[1];
            acc[r] += bp[2] * ct[2];
            acc[r] += bp[3] * ct[3];
            acc[r] += bp[4] * ct[4];
            acc[r] += bp[5] * ct[5];
            acc[r] += bp[6] * ct[6];
            acc[r] += bp[7] * ct[7];
        }
    }
#pragma unroll
    for (int r = 0; r < 16; r++) {
        int row = r0 + r;
        if (row < NR)
            shapeT[(size_t)row * 64 + lane] = acc[r] + meanshape[row];
    }

    // ---------------- texture: texBase (j 0..79) ----------------
#pragma unroll
    for (int r = 0; r < 16; r++) acc[r] = 0.f;

#pragma unroll 2
    for (int jt = 0; jt < 10; jt++) {
        float ct[8];
#pragma unroll
        for (int u = 0; u < 8; u++) ct[u] = ctrT[(jt * 8 + u) * 64 + lane];
#pragma unroll
        for (int r = 0; r < 16; r++) {
            int row = r0 + r; if (row >= NR) row = NR - 1;
            const float* bp = texBase + (size_t)row * 80 + jt * 8;
            acc[r] += bp[0] * ct[0];
            acc[r] += bp[1] * ct[1];
            acc[r] += bp[2] * ct[2];
            acc[r] += bp[3] * ct[3];
            acc[r] += bp[4] * ct[4];
            acc[r] += bp[5] * ct[5];
            acc[r] += bp[6] * ct[6];
            acc[r] += bp[7] * ct[7];
        }
    }
    const float inv255 = 1.0f / 255.0f;
    if (tex_transposed) {
#pragma unroll
        for (int r = 0; r < 16; r++) {
            int row = r0 + r;
            if (row < NR)
                texT[(size_t)row * 64 + lane] = (acc[r] + meantex[row]) * inv255;
        }
    } else {
#pragma unroll
        for (int r = 0; r < 16; r++) {
            int row = r0 + r;
            if (row < NR)
                texT[(size_t)lane * NR + row] = (acc[r] + meantex[row]) * inv255;
        }
    }
}

// wave = one vertex for all 64 batches (lane = batch); 4 waves x 4 vertices per block.
// Two passes (geometry, then color) to keep register live ranges small.
__global__ __launch_bounds__(256) void k_vertex(
    const float* __restrict__ shapeT,  // [i][64]
    const float* __restrict__ texT,    // [i][64] (or out_color layout if tex_in_out)
    const float* __restrict__ rotM, const float* __restrict__ gm,
    const float* __restrict__ coeffs,
    const int* __restrict__ point_buf, const int* __restrict__ face_buf,
    float* __restrict__ out_vertex, float* __restrict__ out_color,
    int tex_in_out)
{
    __shared__ float sh[64 * 49];   // [b][48] padded to 49
    int wave = threadIdx.x >> 6;
    int b    = threadIdx.x & 63;
    int v0   = blockIdx.x * 16;
    int nvalid = N_V - v0; if (nvalid > 16) nvalid = 16;
    int kmax = 3 * nvalid;

    float m0 = rotM[b * 9 + 0], m1 = rotM[b * 9 + 1], m2 = rotM[b * 9 + 2];
    float m3 = rotM[b * 9 + 3], m4 = rotM[b * 9 + 4], m5 = rotM[b * 9 + 5];
    float m6 = rotM[b * 9 + 6], m7 = rotM[b * 9 + 7], m8 = rotM[b * 9 + 8];
    float tx = coeffs[b * 257 + 254], ty = coeffs[b * 257 + 255], tz = coeffs[b * 257 + 256];

    float rn[4][3];   // rotated normals, carried to pass 2

    // ---------------- pass 1: vertices + normals ----------------
#pragma unroll
    for (int vr = 0; vr < 4; vr++) {
        int v = v0 + wave * 4 + vr;
        int vc = (v < N_V) ? v : (N_V - 1);

        float sx0 = shapeT[(size_t)(3 * vc)     * 64 + b];
        float sy0 = shapeT[(size_t)(3 * vc + 1) * 64 + b];
        float sz0 = shapeT[(size_t)(3 * vc + 2) * 64 + b];

        float vx = m0 * sx0 + m1 * sy0 + m2 * sz0 + tx;
        float vy = m3 * sx0 + m4 * sy0 + m5 * sz0 + ty;
        float vz = m6 * sx0 + m7 * sy0 + m8 * sz0 + tz;
        sh[b * 49 + (wave * 4 + vr) * 3 + 0] = vx;
        sh[b * 49 + (wave * 4 + vr) * 3 + 1] = vy;
        sh[b * 49 + (wave * 4 + vr) * 3 + 2] = 10.0f - vz;

        float nx = 0.f, ny = 0.f, nz = 0.f;
#pragma unroll
        for (int k = 0; k < 8; k++) {
            int f = point_buf[vc * 8 + k];
            if (f < N_F) {
                int i0 = face_buf[f * 3], i1 = face_buf[f * 3 + 1], i2 = face_buf[f * 3 + 2];
                float p0x = shapeT[(size_t)(3 * i0)     * 64 + b];
                float p0y = shapeT[(size_t)(3 * i0 + 1) * 64 + b];
                float p0z = shapeT[(size_t)(3 * i0 + 2) * 64 + b];
                float p1x = shapeT[(size_t)(3 * i1)     * 64 + b];
                float p1y = shapeT[(size_t)(3 * i1 + 1) * 64 + b];
                float p1z = shapeT[(size_t)(3 * i1 + 2) * 64 + b];
                float p2x = shapeT[(size_t)(3 * i2)     * 64 + b];
                float p2y = shapeT[(size_t)(3 * i2 + 1) * 64 + b];
                float p2z = shapeT[(size_t)(3 * i2 + 2) * 64 + b];
                float e1x = p0x - p1x, e1y = p0y - p1y, e1z = p0z - p1z;
                float e2x = p1x - p2x, e2y = p1y - p2y, e2z = p1z - p2z;
                float ccx = e1y * e2z - e1z * e2y;
                float ccy = e1z * e2x - e1x * e2z;
                float ccz = e1x * e2y - e1y * e2x;
                float l = sqrtf(ccx * ccx + ccy * ccy + ccz * ccz);
                float inv = 1.0f / fmaxf(l, 1e-12f);
                nx += ccx * inv; ny += ccy * inv; nz += ccz * inv;
            }
        }
        float l = sqrtf(nx * nx + ny * ny + nz * nz);
        float inv = 1.0f / fmaxf(l, 1e-12f);
        nx *= inv; ny *= inv; nz *= inv;

        rn[vr][0] = m0 * nx + m1 * ny + m2 * nz;
        rn[vr][1] = m3 * nx + m4 * ny + m5 * nz;
        rn[vr][2] = m6 * nx + m7 * ny + m8 * nz;
    }

    __syncthreads();
#pragma unroll
    for (int it = 0; it < 12; it++) {
        int f = it * 256 + threadIdx.x;
        int bb = f / 48, k = f - bb * 48;
        if (k < kmax)
            __builtin_nontemporal_store(sh[bb * 49 + k],
                                        out_vertex + (size_t)bb * NR + 3 * (size_t)v0 + k);
    }
    __syncthreads();

    // ---------------- pass 2: colors ----------------
    const float A0C0 = 0.8862269254527580f;
    const float A1C1 = 1.7724538509055159f;
    const float A2C2 = 2.4270323912f;
    const float C6   = 0.7006239022f;
    const float C8   = 1.2135161956f;

    float g[27];
#pragma unroll
    for (int k = 0; k < 27; k++) g[k] = gm[b * 27 + k];

#pragma unroll
    for (int vr = 0; vr < 4; vr++) {
        int v = v0 + wave * 4 + vr;
        int vc = (v < N_V) ? v : (N_V - 1);
        float rx = rn[vr][0], ry = rn[vr][1], rz = rn[vr][2];

        float Y0 = A0C0;
        float Y1 = -A1C1 * ry;
        float Y2 =  A1C1 * rz;
        float Y3 = -A1C1 * rx;
        float Y4 =  A2C2 * rx * ry;
        float Y5 = -A2C2 * ry * rz;
        float Y6 =  C6 * (3.f * rz * rz - 1.f);
        float Y7 = -A2C2 * rx * rz;
        float Y8 =  C8 * (rx * rx - ry * ry);

        float t0, t1, t2;
        if (tex_in_out) {
            size_t ob = (size_t)b * NR + 3 * (size_t)vc;
            t0 = out_color[ob]; t1 = out_color[ob + 1]; t2 = out_color[ob + 2];
        } else {
            t0 = texT[(size_t)(3 * vc)     * 64 + b];
            t1 = texT[(size_t)(3 * vc + 1) * 64 + b];
            t2 = texT[(size_t)(3 * vc + 2) * 64 + b];
        }
        float tex3[3] = {t0, t1, t2};
#pragma unroll
        for (int c = 0; c < 3; c++) {
            float rgb = Y0 * g[0 + c] + Y1 * g[3 + c] + Y2 * g[6 + c] + Y3 * g[9 + c] +
                        Y4 * g[12 + c] + Y5 * g[15 + c] + Y6 * g[18 + c] + Y7 * g[21 + c] +
                        Y8 * g[24 + c];
            sh[b * 49 + (wave * 4 + vr) * 3 + c] = rgb * tex3[c];
        }
    }

    __syncthreads();
#pragma unroll
    for (int it = 0; it < 12; it++) {
        int f = it * 256 + threadIdx.x;
        int bb = f / 48, k = f - bb * 48;
        if (k < kmax)
            __builtin_nontemporal_store(sh[bb * 49 + k],
                                        out_color + (size_t)bb * NR + 3 * (size_t)v0 + k);
    }
}

__global__ __launch_bounds__(64) void k_landmark(
    const float* __restrict__ shapeT, const int* __restrict__ keypoints,
    const float* __restrict__ rotM, const float* __restrict__ coeffs,
    const float* __restrict__ P,
    float* __restrict__ out_lm)
{
    int l = blockIdx.x;
    int b = threadIdx.x;
    int kp = keypoints[l];

    float m0 = rotM[b * 9 + 0], m1 = rotM[b * 9 + 1], m2 = rotM[b * 9 + 2];
    float m3 = rotM[b * 9 + 3], m4 = rotM[b * 9 + 4], m5 = rotM[b * 9 + 5];
    float m6 = rotM[b * 9 + 6], m7 = rotM[b * 9 + 7], m8 = rotM[b * 9 + 8];
    float tx = coeffs[b * 257 + 254], ty = coeffs[b * 257 + 255], tz = coeffs[b * 257 + 256];

    float sx0 = shapeT[(size_t)(3 * kp)     * 64 + b];
    float sy0 = shapeT[(size_t)(3 * kp + 1) * 64 + b];
    float sz0 = shapeT[(size_t)(3 * kp + 2) * 64 + b];

    float x = m0 * sx0 + m1 * sy0 + m2 * sz0 + tx;
    float y = m3 * sx0 + m4 * sy0 + m5 * sz0 + ty;
    float z = 10.0f - (m6 * sx0 + m7 * sy0 + m8 * sz0 + tz);

    float p0 = x * P[0] + y * P[3] + z * P[6];
    float p1 = x * P[1] + y * P[4] + z * P[7];
    float p2 = x * P[2] + y * P[5] + z * P[8];

    size_t o = ((size_t)b * 68 + l) * 2;
    out_lm[o]     = p0 / p2;
    out_lm[o + 1] = p1 / p2;
}

extern "C" void kernel_launch(void* const* d_in, const int* in_sizes, int n_in,
                              void* d_out, int out_size, void* d_ws, size_t ws_size,
                              hipStream_t stream) {
    const float* coeffs    = (const float*)d_in[0];
    const float* meanshape = (const float*)d_in[1];
    const float* idBase    = (const float*)d_in[2];
    const float* exBase    = (const float*)d_in[3];
    const float* meantex   = (const float*)d_in[4];
    const float* texBase   = (const float*)d_in[5];
    const float* persc     = (const float*)d_in[6];
    const float* init_lit  = (const float*)d_in[7];
    const int*   point_buf = (const int*)d_in[8];
    const int*   face_buf  = (const int*)d_in[9];
    const int*   keypoints = (const int*)d_in[10];

    float* ws = (float*)d_ws;
    float* rotM   = ws + WS_ROT;
    float* gm     = ws + WS_GM;
    float* ctrS   = ws + WS_CTRS;
    float* ctrT   = ws + WS_CTRT;
    float* shapeT = ws + WS_SHAPET;

    float* out_vertex = (float*)d_out;
    float* out_color  = out_vertex + (size_t)NB * NR;
    float* out_lm     = out_color  + (size_t)NB * NR;

    size_t need = ((size_t)WS_SHAPET + 2 * (size_t)NR * 64) * sizeof(float);
    int tex_transposed = (ws_size >= need) ? 1 : 0;
    float* texT = tex_transposed ? (shapeT + (size_t)NR * 64) : out_color;

    k_setup_rot<<<1, 64, 0, stream>>>(coeffs, init_lit, rotM, gm);
    k_transpose<<<224, 64, 0, stream>>>(coeffs, ctrS, ctrT);

    int gb = (NR + 63) / 64;   // 1674
    k_gemm<<<gb, 256, 0, stream>>>(idBase, exBase, texBase, meanshape,
                                   meantex, ctrS, ctrT, shapeT, texT,
                                   tex_transposed);

    int vb = (N_V + 15) / 16;  // 2232
    k_vertex<<<vb, 256, 0, stream>>>(shapeT, tex_transposed ? texT : nullptr,
                                     rotM, gm, coeffs, point_buf, face_buf,
                                     out_vertex, out_color, tex_transposed ? 0 : 1);

    k_landmark<<<68, 64, 0, stream>>>(shapeT, keypoints, rotM, coeffs, persc, out_lm);
}